// Round 15
// baseline (93.117 us; speedup 1.0000x reference)
//
#include <hip/hip_runtime.h>

#define M_PAD 512

typedef float f32x4 __attribute__((ext_vector_type(4)));

// Seeded wave-parallel lower_bound over sorted ri[0..T): first idx with
// ri[idx] >= target. Seed window +-4096 around expected pos target*T/N
// (x8 gallop expansion keeps it provably correct), then 65-ary wave rounds.
__device__ __forceinline__ int lower_bound_seeded(const int* __restrict__ ri,
                                                  int T, int N, int target,
                                                  int lane) {
    int guess = (int)(((long long)target * T) / N);
    int W = 4096;
    int lo = max(0, guess - W), hi = min(T, guess + W);
    while (true) {
        bool okLo = (lo == 0) || (ri[lo - 1] < target);
        bool okHi = (hi == T) || (ri[hi] >= target);
        if (okLo && okHi) break;
        W <<= 3;
        lo = max(0, guess - W); hi = min(T, guess + W);
    }
    while (hi - lo > 64) {
        int len = hi - lo;
        int probe = lo + (len * (lane + 1)) / 65;
        int v = ri[probe];
        unsigned long long m = __ballot(v < target);
        int k = __popcll(m);
        int nlo = (k == 0)  ? lo : lo + (len * k) / 65;
        int nhi = (k == 64) ? hi : lo + (len * (k + 1)) / 65;
        lo = nlo; hi = nhi;
    }
    int p = lo + lane;
    int v = (p < hi) ? ri[p] : 2147483647;
    unsigned long long m = __ballot(v < target);
    return lo + __popcll(m);
}

// One dispatch, two CONCURRENT block families (uniform branch on blockIdx):
//  W-region (bid < N*2): half-ray blocks, 2 searches, write ONLY the 16B
//    streams: xyz_out (valid) + xyz_w (all). Same store shape as the 69us
//    best kernel.
//  V-region (bid >= N*2): 2-ray blocks, 3 searches, gather ts/te (L3-hot,
//    33.6MB << 256MB LLC) and write z_vals/dists/ray_valid as DENSE f32x4:
//    every wave-instr = 1KB run on ONE stream (H3: stream purity).
__global__ __launch_bounds__(256)
void mono_kernel(const float* __restrict__ rays,
                 const int* __restrict__ ri,
                 const float* __restrict__ ts,
                 const float* __restrict__ te,
                 float* __restrict__ xyz_out,     // (T,4)
                 float* __restrict__ ray_valid,   // (N,512)
                 float* __restrict__ z_vals,      // (N,512)
                 float* __restrict__ dists,       // (N,512)
                 float* __restrict__ xyz_w,       // (N,512,4)
                 float* __restrict__ whole_valid, // (N,)
                 int N, int T) {
    const int tid = threadIdx.x;
    const int wave = tid >> 6, lane = tid & 63;
    const int GW = N * 2;
    __shared__ int sh[3];

    if ((int)blockIdx.x < GW) {
        // ---- W-region: 16B/lane streams, half ray per block ----
        const int b = blockIdx.x;
        const int r = b >> 1, h = b & 1;
        if (wave < 2) {
            int lb = lower_bound_seeded(ri, T, N, r + wave, lane);
            if (lane == 0) sh[wave] = lb;
        }
        __syncthreads();
        const int s = sh[0], cnt = sh[1] - s;
        const int j = h * 256 + tid;

        f32x4 pt = {0.f, 0.f, 0.f, 0.f};
        if (j < cnt) {
            int i = s + j;
            float a = ts[i], bb = te[i];          // dense lane-consecutive
            float z = (a + bb) * 0.5f;
            const float* rc = rays + (size_t)r * 6;
            pt.x = fmaf(z, rc[3], rc[0]);
            pt.y = fmaf(z, rc[4], rc[1]);
            pt.z = fmaf(z, rc[5], rc[2]);
            __builtin_nontemporal_store(pt, reinterpret_cast<f32x4*>(xyz_out) + i);
        }
        __builtin_nontemporal_store(pt,
            reinterpret_cast<f32x4*>(xyz_w) + ((size_t)r << 9) + j);
    } else {
        // ---- V-region: scalar streams as dense f32x4, 2 rays per block ----
        const int b = blockIdx.x - GW;
        const int r0 = b * 2;
        if (wave < 3) {
            int lb = lower_bound_seeded(ri, T, N, r0 + wave, lane);
            if (lane == 0) sh[wave] = lb;
        }
        __syncthreads();
        const int k = tid >> 7;              // local ray 0/1
        const int local = tid & 127;
        const int j0 = local << 2;           // 4 slots per thread
        const int r = r0 + k;
        const int s = sh[k];
        const int cnt = sh[k + 1] - s;

        f32x4 z4 = {0.f, 0.f, 0.f, 0.f};
        f32x4 d4 = {0.f, 0.f, 0.f, 0.f};
        f32x4 v4 = {0.f, 0.f, 0.f, 0.f};
        #pragma unroll
        for (int e = 0; e < 4; ++e) {
            int j = j0 + e;
            if (j < cnt) {
                int i = s + j;
                float a = ts[i], bb = te[i];     // L3-resident re-gather
                z4[e] = (a + bb) * 0.5f;
                d4[e] = bb - a;
                v4[e] = 1.0f;
            }
        }
        size_t base4 = ((size_t)r << 7) + local;   // (r*512 + j0)/4
        __builtin_nontemporal_store(z4, reinterpret_cast<f32x4*>(z_vals)    + base4);
        __builtin_nontemporal_store(d4, reinterpret_cast<f32x4*>(dists)     + base4);
        __builtin_nontemporal_store(v4, reinterpret_cast<f32x4*>(ray_valid) + base4);

        if (tid == 0)   whole_valid[r0]     = 1.0f;
        if (tid == 128) whole_valid[r0 + 1] = 1.0f;
    }
}

extern "C" void kernel_launch(void* const* d_in, const int* in_sizes, int n_in,
                              void* d_out, int out_size, void* d_ws, size_t ws_size,
                              hipStream_t stream) {
    const float* rays = (const float*)d_in[0];  // (N,6)
    const int*   ri   = (const int*)d_in[1];    // (T,) sorted
    const float* ts   = (const float*)d_in[2];  // (T,)
    const float* te   = (const float*)d_in[3];  // (T,)
    const int N = in_sizes[0] / 6;
    const int T = in_sizes[1];

    float* out         = (float*)d_out;
    float* xyz_out     = out;                                    // T*4
    float* ray_valid   = xyz_out + (size_t)T * 4;                // N*512
    float* z_vals      = ray_valid + (size_t)N * M_PAD;          // N*512
    float* dists       = z_vals + (size_t)N * M_PAD;             // N*512
    float* whole_valid = dists + (size_t)N * M_PAD;              // N
    float* xyz_w       = whole_valid + N;                        // N*512*4

    const int grid = N * 2 + N / 2;
    mono_kernel<<<grid, 256, 0, stream>>>(rays, ri, ts, te,
                                          xyz_out, ray_valid, z_vals,
                                          dists, xyz_w, whole_valid, N, T);
}

// Round 16
// 75.834 us; speedup vs baseline: 1.2279x; 1.2279x over previous
//
#include <hip/hip_runtime.h>

#define M_PAD 512

typedef float f32x4 __attribute__((ext_vector_type(4)));

// Seeded wave-parallel lower_bound over sorted ri[0..T): first idx with
// ri[idx] >= target. Seed window +-4096 around expected pos target*T/N
// (x8 gallop expansion keeps it provably correct), then 65-ary wave rounds.
__device__ __forceinline__ int lower_bound_seeded(const int* __restrict__ ri,
                                                  int T, int N, int target,
                                                  int lane) {
    int guess = (int)(((long long)target * T) / N);
    int W = 4096;
    int lo = max(0, guess - W), hi = min(T, guess + W);
    while (true) {
        bool okLo = (lo == 0) || (ri[lo - 1] < target);
        bool okHi = (hi == T) || (ri[hi] >= target);
        if (okLo && okHi) break;
        W <<= 3;
        lo = max(0, guess - W); hi = min(T, guess + W);
    }
    while (hi - lo > 64) {
        int len = hi - lo;
        int probe = lo + (len * (lane + 1)) / 65;
        int v = ri[probe];
        unsigned long long m = __ballot(v < target);
        int k = __popcll(m);
        int nlo = (k == 0)  ? lo : lo + (len * k) / 65;
        int nhi = (k == 64) ? hi : lo + (len * (k + 1)) / 65;
        lo = nlo; hi = nhi;
    }
    int p = lo + lane;
    int v = (p < hi) ? ri[p] : 2147483647;
    unsigned long long m = __ballot(v < target);
    return lo + __popcll(m);
}

// R12 structure (single dispatch, block = half ray, 2 searches/block,
// dense gather i=s+j, nt stores) with ONE change: the three 4B scalar
// streams (z/d/valid) are staged in LDS (3KB) and flushed by waves 0..2
// as single f32x4 stores -> each wave-instr is a pure 1KB run on one
// stream (was 3 interleaved 256B-run instrs per wave).
__global__ __launch_bounds__(256)
void mono_kernel(const float* __restrict__ rays,
                 const int* __restrict__ ri,
                 const float* __restrict__ ts,
                 const float* __restrict__ te,
                 float* __restrict__ xyz_out,     // (T,4)
                 float* __restrict__ ray_valid,   // (N,512)
                 float* __restrict__ z_vals,      // (N,512)
                 float* __restrict__ dists,       // (N,512)
                 float* __restrict__ xyz_w,       // (N,512,4)
                 float* __restrict__ whole_valid, // (N,)
                 int N, int T) {
    const int b = blockIdx.x;
    const int r = b >> 1;
    const int h = b & 1;
    const int tid = threadIdx.x;
    const int wave = tid >> 6, lane = tid & 63;

    __shared__ int sh[2];
    __shared__ float lz[256], ld[256], lv[256];

    if (wave < 2) {
        int lb = lower_bound_seeded(ri, T, N, r + wave, lane);
        if (lane == 0) sh[wave] = lb;
    }
    __syncthreads();
    const int s = sh[0];
    const int cnt = sh[1] - s;

    const int j = h * 256 + tid;

    float z = 0.0f, dd = 0.0f, v = 0.0f;
    f32x4 pt = {0.f, 0.f, 0.f, 0.f};

    if (j < cnt) {
        int i = s + j;
        float a = ts[i], bb = te[i];          // dense: lane-consecutive i
        z  = (a + bb) * 0.5f;
        dd = bb - a;
        v  = 1.0f;
        const float* rc = rays + (size_t)r * 6;   // wave-uniform -> broadcast
        pt.x = fmaf(z, rc[3], rc[0]);
        pt.y = fmaf(z, rc[4], rc[1]);
        pt.z = fmaf(z, rc[5], rc[2]);
        __builtin_nontemporal_store(pt, reinterpret_cast<f32x4*>(xyz_out) + i);
    }
    __builtin_nontemporal_store(pt,
        reinterpret_cast<f32x4*>(xyz_w) + ((size_t)r << 9) + j);

    lz[tid] = z; ld[tid] = dd; lv[tid] = v;
    if (j == 0) whole_valid[r] = 1.0f;
    __syncthreads();

    // Flush phase: waves 0..2 each own ONE stream, one f32x4/lane (1KB run).
    const size_t gslot = ((size_t)r << 9) + h * 256;   // 256-slot base, 16B-aligned
    if (wave == 0) {
        f32x4 x = *reinterpret_cast<f32x4*>(&lz[lane << 2]);
        __builtin_nontemporal_store(x, reinterpret_cast<f32x4*>(z_vals + gslot) + lane);
    } else if (wave == 1) {
        f32x4 x = *reinterpret_cast<f32x4*>(&ld[lane << 2]);
        __builtin_nontemporal_store(x, reinterpret_cast<f32x4*>(dists + gslot) + lane);
    } else if (wave == 2) {
        f32x4 x = *reinterpret_cast<f32x4*>(&lv[lane << 2]);
        __builtin_nontemporal_store(x, reinterpret_cast<f32x4*>(ray_valid + gslot) + lane);
    }
}

extern "C" void kernel_launch(void* const* d_in, const int* in_sizes, int n_in,
                              void* d_out, int out_size, void* d_ws, size_t ws_size,
                              hipStream_t stream) {
    const float* rays = (const float*)d_in[0];  // (N,6)
    const int*   ri   = (const int*)d_in[1];    // (T,) sorted
    const float* ts   = (const float*)d_in[2];  // (T,)
    const float* te   = (const float*)d_in[3];  // (T,)
    const int N = in_sizes[0] / 6;
    const int T = in_sizes[1];

    float* out         = (float*)d_out;
    float* xyz_out     = out;                                    // T*4
    float* ray_valid   = xyz_out + (size_t)T * 4;                // N*512
    float* z_vals      = ray_valid + (size_t)N * M_PAD;          // N*512
    float* dists       = z_vals + (size_t)N * M_PAD;             // N*512
    float* whole_valid = dists + (size_t)N * M_PAD;              // N
    float* xyz_w       = whole_valid + N;                        // N*512*4

    mono_kernel<<<N * 2, 256, 0, stream>>>(rays, ri, ts, te,
                                           xyz_out, ray_valid, z_vals,
                                           dists, xyz_w, whole_valid, N, T);
}

// Round 17
// 69.120 us; speedup vs baseline: 1.3472x; 1.0971x over previous
//
#include <hip/hip_runtime.h>

#define M_PAD 512

typedef float f32x4 __attribute__((ext_vector_type(4)));

// Wave-parallel lower_bound over sorted ri[0..Tn): first idx with ri[idx] >= target.
// 65-ary partition per round: 64 lanes probe interior points, ballot gives the
// bracket. len shrinks ~65x/round: 4.19M -> 64K -> 1K -> 16 -> linear finish.
__device__ __forceinline__ int lower_bound_wave(const int* __restrict__ ri,
                                                int Tn, int target, int lane) {
    int lo = 0, hi = Tn;
    while (hi - lo > 64) {
        int len = hi - lo;
        int probe = lo + (len * (lane + 1)) / 65;       // strictly inside (lo,hi)
        int v = ri[probe];
        unsigned long long m = __ballot(v < target);     // prefix mask (sorted)
        int k = __popcll(m);
        int nlo = (k == 0)  ? lo : lo + (len * k) / 65;
        int nhi = (k == 64) ? hi : lo + (len * (k + 1)) / 65;
        lo = nlo; hi = nhi;
    }
    int p = lo + lane;
    int v = (p < hi) ? ri[p] : 2147483647;               // sentinel >= any target
    unsigned long long m = __ballot(v < target);
    return lo + __popcll(m);
}

// Single-dispatch fused kernel (best measured: 68.9 us). Block b covers half
// a ray: r = b>>1, slots j in [(b&1)*256, (b&1)*256+256). Waves 0/1 search
// start=LB(r), end=LB(r+1); then one slot per thread, dense lane-consecutive
// gather i=s+j, nontemporal stores (write-once outputs bypass L2 allocation).
__global__ __launch_bounds__(256)
void mono_kernel(const float* __restrict__ rays,
                 const int* __restrict__ ri,
                 const float* __restrict__ ts,
                 const float* __restrict__ te,
                 float* __restrict__ xyz_out,     // (T,4)
                 float* __restrict__ ray_valid,   // (N,512)
                 float* __restrict__ z_vals,      // (N,512)
                 float* __restrict__ dists,       // (N,512)
                 float* __restrict__ xyz_w,       // (N,512,4)
                 float* __restrict__ whole_valid, // (N,)
                 int T) {
    const int b = blockIdx.x;
    const int r = b >> 1;
    const int h = b & 1;
    const int tid = threadIdx.x;
    const int wave = tid >> 6, lane = tid & 63;

    __shared__ int sh[2];
    if (wave < 2) {
        int lb = lower_bound_wave(ri, T, r + wave, lane);
        if (lane == 0) sh[wave] = lb;
    }
    __syncthreads();
    const int s = sh[0];
    const int cnt = sh[1] - s;

    const int j = h * 256 + tid;
    const int idx = (r << 9) + j;

    float z = 0.0f, dd = 0.0f, v = 0.0f;
    f32x4 pt = {0.f, 0.f, 0.f, 0.f};

    if (j < cnt) {
        int i = s + j;
        float a = ts[i], bb = te[i];          // dense: lane-consecutive i
        z  = (a + bb) * 0.5f;
        dd = bb - a;
        v  = 1.0f;
        const float* rc = rays + (size_t)r * 6;   // wave-uniform -> broadcast
        pt.x = fmaf(z, rc[3], rc[0]);
        pt.y = fmaf(z, rc[4], rc[1]);
        pt.z = fmaf(z, rc[5], rc[2]);
        __builtin_nontemporal_store(pt, reinterpret_cast<f32x4*>(xyz_out) + i);
    }

    __builtin_nontemporal_store(z,  &z_vals[idx]);
    __builtin_nontemporal_store(dd, &dists[idx]);
    __builtin_nontemporal_store(v,  &ray_valid[idx]);
    __builtin_nontemporal_store(pt, reinterpret_cast<f32x4*>(xyz_w) + idx);

    if (j == 0) whole_valid[r] = 1.0f;
}

extern "C" void kernel_launch(void* const* d_in, const int* in_sizes, int n_in,
                              void* d_out, int out_size, void* d_ws, size_t ws_size,
                              hipStream_t stream) {
    const float* rays = (const float*)d_in[0];  // (N,6)
    const int*   ri   = (const int*)d_in[1];    // (T,) sorted
    const float* ts   = (const float*)d_in[2];  // (T,)
    const float* te   = (const float*)d_in[3];  // (T,)
    const int N = in_sizes[0] / 6;
    const int T = in_sizes[1];

    float* out         = (float*)d_out;
    float* xyz_out     = out;                                    // T*4
    float* ray_valid   = xyz_out + (size_t)T * 4;                // N*512
    float* z_vals      = ray_valid + (size_t)N * M_PAD;          // N*512
    float* dists       = z_vals + (size_t)N * M_PAD;             // N*512
    float* whole_valid = dists + (size_t)N * M_PAD;              // N
    float* xyz_w       = whole_valid + N;                        // N*512*4

    mono_kernel<<<N * 2, 256, 0, stream>>>(rays, ri, ts, te,
                                           xyz_out, ray_valid, z_vals,
                                           dists, xyz_w, whole_valid, T);
}